// Round 5
// baseline (1743.606 us; speedup 1.0000x reference)
//
#include <hip/hip_runtime.h>
#include <hip/hip_bf16.h>

#define BB 8
#define NN 2048
#define DD 128
#define NSTEPS 16
#define DT_F 0.1f
#define TWO_PI_F 6.283185307179586f
#define LDP 136   // B-staging row stride (bf16 elems)
#define CST 520   // C-chunk row stride (bf16 elems)

typedef short short8 __attribute__((ext_vector_type(8)));
typedef float floatx4 __attribute__((ext_vector_type(4)));

// ---------------- K0: split fp32 embeddings into bf16 hi/lo ----------------
__global__ void split_kernel(const float* __restrict__ e,
                             __hip_bfloat16* __restrict__ hi,
                             __hip_bfloat16* __restrict__ lo) {
    int i = blockIdx.x * 256 + threadIdx.x;
    float x = e[i];
    __hip_bfloat16 h = __float2bfloat16(x);
    hi[i] = h;
    lo[i] = __float2bfloat16(x - __bfloat162float(h));
}

// ---- manual per-batch barrier (64 blocks/batch, monotonic counter) --------
// Requires all 512 blocks co-resident: 2 blocks/CU by launch_bounds(256,2)
// (VGPR<=256 -> 2 waves/SIMD) + LDS 68096*2 <= 160K. Guarded spin: a
// co-residency failure degrades to a wrong answer, not a hang.
__device__ __forceinline__ void batch_barrier(unsigned* cnt, int gen) {
    __syncthreads();                       // all waves' stores drained (vmcnt)
    if (threadIdx.x == 0) {
        __hip_atomic_fetch_add(cnt, 1u, __ATOMIC_RELEASE, __HIP_MEMORY_SCOPE_AGENT);
        const unsigned target = 64u * (unsigned)gen;
        int guard = 0;
        while (__hip_atomic_load(cnt, __ATOMIC_RELAXED, __HIP_MEMORY_SCOPE_AGENT) < target
               && guard < (1 << 24)) {
            __builtin_amdgcn_s_sleep(2);
            ++guard;
        }
    }
    __threadfence();                       // agent acquire: inv L1/L2 stale lines
    __syncthreads();
}

// ---------------- fused: build C in registers, run all 16 steps ------------
// 512 blocks x 256 thr (2/CU). Block owns 32 rows of one batch; each wave
// owns 8 rows of C, bf16-packed in 128 VGPRs (creg).
__launch_bounds__(256, 2)
__global__ void fused_kernel(const __hip_bfloat16* __restrict__ Ehi,
                             const __hip_bfloat16* __restrict__ Elo,
                             const float* __restrict__ theta0,
                             const float* __restrict__ omega,
                             float* __restrict__ tA,
                             float* __restrict__ tB,
                             float* __restrict__ out,
                             unsigned* __restrict__ barrier_cnt) {
    __shared__ __align__(16) char smem[68096];
    __hip_bfloat16* Bh = (__hip_bfloat16*)smem;            // 17408 B (phase 1)
    __hip_bfloat16* Bl = (__hip_bfloat16*)(smem + 17408);  // 17408 B (phase 1)
    __hip_bfloat16* Cc = (__hip_bfloat16*)(smem + 34816);  // 33280 B (phase 1)
    float2*         cs = (float2*)smem;                    // 16384 B (phase 2)

    const int tid  = threadIdx.x;
    const int lane = tid & 63;
    const int wave = tid >> 6;
    const int l16  = lane & 15;
    const int quad = lane >> 4;

    const int b    = blockIdx.x >> 6;      // batch
    const int rg   = blockIdx.x & 63;
    const int row0 = rg * 32;              // row base within batch
    const int art  = wave & 1;             // phase-1 row-tile (16 rows)
    const int ctb  = (wave >> 1) * 2;      // phase-1 col-tile base {0,2}

    const __hip_bfloat16* Eb_h = Ehi + (size_t)b * NN * DD;
    const __hip_bfloat16* Eb_l = Elo + (size_t)b * NN * DD;

    // A fragments for this wave's row-tile (held all of phase 1)
    short8 ah[4], al[4];
    {
        const __hip_bfloat16* ph = Eb_h + (size_t)(row0 + art * 16 + l16) * DD + quad * 8;
        const __hip_bfloat16* pl = Eb_l + (size_t)(row0 + art * 16 + l16) * DD + quad * 8;
        #pragma unroll
        for (int kt = 0; kt < 4; ++kt) {
            ah[kt] = *(const short8*)(ph + kt * 32);
            al[kt] = *(const short8*)(pl + kt * 32);
        }
    }
    float tn2[4];
    #pragma unroll
    for (int i = 0; i < 4; ++i) {
        int rr = row0 + art * 16 + quad * 4 + i;
        tn2[i] = 2.0f * (__bfloat162float(Eb_h[(size_t)rr * DD]) +
                         __bfloat162float(Eb_l[(size_t)rr * DD]));
    }

    unsigned creg[8][16];   // 8 rows x 32 cols/lane, bf16-packed

    // ---- phase 1: 4 chunks of 512 cols, 8 sub-chunks of 64 cols each ----
    #pragma unroll 1
    for (int ch = 0; ch < 4; ++ch) {
        for (int sc = 0; sc < 8; ++sc) {
            const int m0 = ch * 512 + sc * 64;
            {
                const __hip_bfloat16* sh = Eb_h + (size_t)m0 * DD;
                const __hip_bfloat16* sl = Eb_l + (size_t)m0 * DD;
                #pragma unroll
                for (int i = 0; i < 4; ++i) {
                    int c   = tid + 256 * i;
                    int row = c >> 4;
                    int col = (c & 15) * 8;
                    *(uint4*)(Bh + row * LDP + col) = *(const uint4*)(sh + row * DD + col);
                    *(uint4*)(Bl + row * LDP + col) = *(const uint4*)(sl + row * DD + col);
                }
            }
            __syncthreads();
            #pragma unroll
            for (int t = 0; t < 2; ++t) {
                const int ct = ctb + t;
                floatx4 acc = {0.f, 0.f, 0.f, 0.f};
                #pragma unroll
                for (int kt = 0; kt < 4; ++kt) {
                    const int ko = kt * 32 + quad * 8;
                    short8 bh = *(const short8*)(Bh + (ct * 16 + l16) * LDP + ko);
                    short8 bl = *(const short8*)(Bl + (ct * 16 + l16) * LDP + ko);
                    acc = __builtin_amdgcn_mfma_f32_16x16x32_bf16(ah[kt], bh, acc, 0, 0, 0);
                    acc = __builtin_amdgcn_mfma_f32_16x16x32_bf16(ah[kt], bl, acc, 0, 0, 0);
                    acc = __builtin_amdgcn_mfma_f32_16x16x32_bf16(al[kt], bh, acc, 0, 0, 0);
                }
                float tm = __bfloat162float(Bh[(ct * 16 + l16) * LDP]) +
                           __bfloat162float(Bl[(ct * 16 + l16) * LDP]);
                #pragma unroll
                for (int i = 0; i < 4; ++i) {
                    float arg = fmaxf(fmaf(tn2[i], tm, -acc[i]), 1.0f + 1e-7f);
                    float s   = sqrtf(fmaf(arg, arg, -1.0f));
                    float cp  = __builtin_amdgcn_rcpf(arg + s);  // exp(-acosh(arg))
                    int lrow  = art * 16 + quad * 4 + i;
                    int ccol  = sc * 64 + ct * 16 + l16;
                    Cc[lrow * CST + ccol] = __float2bfloat16(fminf(cp, 1.0f));
                }
            }
            __syncthreads();
        }
        // read back chunk into creg (row = wave*8+r, cols = ch*512 + lane*8..+7)
        #pragma unroll
        for (int r = 0; r < 8; ++r) {
            int lrow = wave * 8 + r;
            uint4 v = *(const uint4*)(Cc + lrow * CST + lane * 8);
            creg[r][ch * 4 + 0] = v.x;
            creg[r][ch * 4 + 1] = v.y;
            creg[r][ch * 4 + 2] = v.z;
            creg[r][ch * 4 + 3] = v.w;
        }
        // next chunk's post-stage __syncthreads orders readback vs Cc overwrite
    }

    // ---- phase 2: 16 steps from register-resident C ----
    const float inv = 1.0f / NN;
    unsigned* cnt = barrier_cnt + b;
    #pragma unroll 1
    for (int s = 0; s < NSTEPS; ++s) {
        const float* tin = (s == 0) ? (theta0 + b * NN)
                                    : (((s & 1) ? tA : tB) + b * NN);
        float* tout = (s == NSTEPS - 1) ? (out + b * NN)
                                        : (((s & 1) ? tB : tA) + b * NN);

        __syncthreads();   // cs region free (phase 1 / prev step's reads done)
        #pragma unroll
        for (int i = 0; i < 8; ++i) {
            int m = tid + 256 * i;
            float sv, cv;
            __sincosf(tin[m], &sv, &cv);
            cs[m] = make_float2(cv, sv);
        }
        __syncthreads();

        float sumc[8] = {0, 0, 0, 0, 0, 0, 0, 0};
        float sums[8] = {0, 0, 0, 0, 0, 0, 0, 0};
        #pragma unroll
        for (int j = 0; j < 4; ++j) {
            float ccj[8], ssj[8];
            #pragma unroll
            for (int i = 0; i < 8; ++i) {
                float2 v = cs[j * 512 + lane * 8 + i];
                ccj[i] = v.x;
                ssj[i] = v.y;
            }
            #pragma unroll
            for (int r = 0; r < 8; ++r) {
                #pragma unroll
                for (int k = 0; k < 4; ++k) {
                    unsigned u = creg[r][j * 4 + k];
                    float f0 = __uint_as_float(u << 16);
                    float f1 = __uint_as_float(u & 0xffff0000u);
                    sumc[r] = fmaf(f0, ccj[2 * k],     sumc[r]);
                    sums[r] = fmaf(f0, ssj[2 * k],     sums[r]);
                    sumc[r] = fmaf(f1, ccj[2 * k + 1], sumc[r]);
                    sums[r] = fmaf(f1, ssj[2 * k + 1], sums[r]);
                }
            }
        }
        #pragma unroll
        for (int r = 0; r < 8; ++r) {
            #pragma unroll
            for (int off = 32; off >= 1; off >>= 1) {
                sumc[r] += __shfl_xor(sumc[r], off, 64);
                sums[r] += __shfl_xor(sums[r], off, 64);
            }
        }
        #pragma unroll
        for (int r = 0; r < 8; ++r) {
            if (lane == r) {
                int nloc = row0 + wave * 8 + r;
                float2 csn = cs[nloc];
                float sum  = csn.y * sumc[r] - csn.x * sums[r];
                float th   = tin[nloc];
                float dth  = omega[nloc] + inv * sum;
                tout[nloc] = fmodf(th + DT_F * dth, TWO_PI_F);
            }
        }
        if (s < NSTEPS - 1) batch_barrier(cnt, s + 1);
    }
}

// ---------------- launch ----------------------------------------------------
extern "C" void kernel_launch(void* const* d_in, const int* in_sizes, int n_in,
                              void* d_out, int out_size, void* d_ws, size_t ws_size,
                              hipStream_t stream) {
    const float* theta0 = (const float*)d_in[0];
    const float* emb    = (const float*)d_in[1];
    const float* omega  = (const float*)d_in[2];
    float* out = (float*)d_out;

    char* ws = (char*)d_ws;
    __hip_bfloat16* Ehi = (__hip_bfloat16*)ws;                    // 4 MiB
    __hip_bfloat16* Elo = (__hip_bfloat16*)(ws + (4 << 20));      // 4 MiB
    float* tA     = (float*)(ws + (8 << 20));                     // 64 KiB
    float* tB     = (float*)(ws + (8 << 20) + 65536);             // 64 KiB
    unsigned* cnt = (unsigned*)(ws + (8 << 20) + 131072);         // 8 counters

    hipMemsetAsync(cnt, 0, BB * sizeof(unsigned), stream);

    split_kernel<<<(BB * NN * DD) / 256, 256, 0, stream>>>(emb, Ehi, Elo);

    fused_kernel<<<dim3(512), dim3(256), 0, stream>>>(Ehi, Elo, theta0, omega,
                                                      tA, tB, out, cnt);
}